// Round 11
// baseline (505.673 us; speedup 1.0000x reference)
//
#include <hip/hip_runtime.h>
#include <math.h>

#define MROWS 12544        // B*N = 64*196
#define KDIM  768
#define EMB   32
#define NCODE 8192
#define ZQ_ELEMS 401408    // 64*32*14*14

// ---------------------------------------------------------------------------
// K0: normalize codebook rows; also store ||e||^2 (post-normalization, as ref)
// ---------------------------------------------------------------------------
__global__ __launch_bounds__(256) void k0_norm_codebook(
    const float* __restrict__ cb, float* __restrict__ em, float* __restrict__ n2)
{
    const int t = threadIdx.x;
    const int c = t & 31;
    const int r = blockIdx.x * 8 + (t >> 5);
    float v = cb[r * 32 + c];
    float s = v * v;
    #pragma unroll
    for (int off = 16; off; off >>= 1) s += __shfl_xor(s, off, 32);
    float e = v / sqrtf(s + 1e-12f);
    em[r * 32 + c] = e;
    float s2 = e * e;
    #pragma unroll
    for (int off = 16; off; off >>= 1) s2 += __shfl_xor(s2, off, 32);
    if (c == 0) n2[r] = s2;
}

// ---------------------------------------------------------------------------
// K1: H = tanh(X @ W1^T + b1).  R4 operating point (PROVEN, do not touch):
// 64x128 tile, BK=16, 256 threads, 4x8 microtile, one-arg launch_bounds ->
// VGPR 128, 4 waves/SIMD, 248us. LDS-issue-bound; any acc>32 microtile
// crosses the 128-VGPR cliff to 2 waves/SIMD and loses (R8/R9).
// ---------------------------------------------------------------------------
#define BM1 64
#define BN1 128
#define BK1 16

__global__ __launch_bounds__(256) void k1_gemm_tanh(
    const float* __restrict__ A, const float* __restrict__ W,
    const float* __restrict__ bias, float* __restrict__ H)
{
    __shared__ __align__(16) float As[2][BK1][68];
    __shared__ __align__(16) float Bs[2][BK1][132];

    const int t    = threadIdx.x;
    const int row0 = blockIdx.x * BM1;
    const int col0 = blockIdx.y * BN1;
    const int tc   = t & 15;          // col group: cols tc*4..+3 and 64+tc*4..+3
    const int tr   = t >> 4;          // row group: rows tr*4..+3

    const int am = t >> 2, ak = (t & 3) * 4;   // A stage: row am, k ak..ak+3
    const int bn = t >> 1, bk = (t & 1) * 8;   // B stage: row bn, k bk..bk+7

    const float* Ap = A + (size_t)(row0 + am) * KDIM + ak;
    const float* Bp = W + (size_t)(col0 + bn) * KDIM + bk;

    float acc[4][8];
    #pragma unroll
    for (int i = 0; i < 4; ++i)
        #pragma unroll
        for (int j = 0; j < 8; ++j) acc[i][j] = 0.f;

    // preload tile 0 (transposed into LDS)
    {
        float4 a  = *(const float4*)(Ap);
        float4 b0 = *(const float4*)(Bp);
        float4 b1 = *(const float4*)(Bp + 4);
        As[0][ak+0][am] = a.x;  As[0][ak+1][am] = a.y;  As[0][ak+2][am] = a.z;  As[0][ak+3][am] = a.w;
        Bs[0][bk+0][bn] = b0.x; Bs[0][bk+1][bn] = b0.y; Bs[0][bk+2][bn] = b0.z; Bs[0][bk+3][bn] = b0.w;
        Bs[0][bk+4][bn] = b1.x; Bs[0][bk+5][bn] = b1.y; Bs[0][bk+6][bn] = b1.z; Bs[0][bk+7][bn] = b1.w;
    }
    __syncthreads();

    const int nkt = KDIM / BK1;   // 48
    int buf = 0;
    for (int kt = 0; kt < nkt; ++kt) {
        float4 na, nb0, nb1;
        const bool pf = (kt + 1 < nkt);
        if (pf) {
            const int ko = (kt + 1) * BK1;
            na  = *(const float4*)(Ap + ko);
            nb0 = *(const float4*)(Bp + ko);
            nb1 = *(const float4*)(Bp + ko + 4);
        }
        #pragma unroll
        for (int k = 0; k < BK1; ++k) {
            float4 av  = *(const float4*)&As[buf][k][tr * 4];
            float4 bv0 = *(const float4*)&Bs[buf][k][tc * 4];
            float4 bv1 = *(const float4*)&Bs[buf][k][tc * 4 + 64];
            float a_[4] = {av.x, av.y, av.z, av.w};
            float b_[8] = {bv0.x, bv0.y, bv0.z, bv0.w, bv1.x, bv1.y, bv1.z, bv1.w};
            #pragma unroll
            for (int i = 0; i < 4; ++i)
                #pragma unroll
                for (int j = 0; j < 8; ++j)
                    acc[i][j] = fmaf(a_[i], b_[j], acc[i][j]);
        }
        if (pf) {
            const int nb = buf ^ 1;
            As[nb][ak+0][am] = na.x;  As[nb][ak+1][am] = na.y;  As[nb][ak+2][am] = na.z;  As[nb][ak+3][am] = na.w;
            Bs[nb][bk+0][bn] = nb0.x; Bs[nb][bk+1][bn] = nb0.y; Bs[nb][bk+2][bn] = nb0.z; Bs[nb][bk+3][bn] = nb0.w;
            Bs[nb][bk+4][bn] = nb1.x; Bs[nb][bk+5][bn] = nb1.y; Bs[nb][bk+6][bn] = nb1.z; Bs[nb][bk+7][bn] = nb1.w;
        }
        __syncthreads();
        buf ^= 1;
    }

    float4 bc0 = *(const float4*)&bias[col0 + tc * 4];
    float4 bc1 = *(const float4*)&bias[col0 + 64 + tc * 4];
    #pragma unroll
    for (int i = 0; i < 4; ++i) {
        const int row = row0 + tr * 4 + i;
        float o0 = tanhf(acc[i][0] + bc0.x);
        float o1 = tanhf(acc[i][1] + bc0.y);
        float o2 = tanhf(acc[i][2] + bc0.z);
        float o3 = tanhf(acc[i][3] + bc0.w);
        float o4 = tanhf(acc[i][4] + bc1.x);
        float o5 = tanhf(acc[i][5] + bc1.y);
        float o6 = tanhf(acc[i][6] + bc1.z);
        float o7 = tanhf(acc[i][7] + bc1.w);
        *(float4*)&H[(size_t)row * KDIM + col0 + tc * 4]      = make_float4(o0, o1, o2, o3);
        *(float4*)&H[(size_t)row * KDIM + col0 + 64 + tc * 4] = make_float4(o4, o5, o6, o7);
    }
}

// ---------------------------------------------------------------------------
// K2: Z = l2norm(H @ W2^T + b2).  32 rows/block -> 392 blocks.
// ---------------------------------------------------------------------------
#define K2C 64
__global__ __launch_bounds__(256) void k2_gemm_norm(
    const float* __restrict__ H, const float* __restrict__ W2,
    const float* __restrict__ b2, float* __restrict__ Z)
{
    __shared__ __align__(16) float As2[32][68];
    __shared__ __align__(16) float Ws2[32][68];

    const int t    = threadIdx.x;
    const int row0 = blockIdx.x * 32;
    const int cg   = t & 7;
    const int rg   = t >> 3;

    float acc[4] = {0.f, 0.f, 0.f, 0.f};

    for (int kc = 0; kc < KDIM; kc += K2C) {
        __syncthreads();
        {
            const int r = t >> 3, kq = (t & 7) * 8;
            *(float4*)&As2[r][kq]     = *(const float4*)&H[(size_t)(row0 + r) * KDIM + kc + kq];
            *(float4*)&As2[r][kq + 4] = *(const float4*)&H[(size_t)(row0 + r) * KDIM + kc + kq + 4];
            *(float4*)&Ws2[r][kq]     = *(const float4*)&W2[(size_t)r * KDIM + kc + kq];
            *(float4*)&Ws2[r][kq + 4] = *(const float4*)&W2[(size_t)r * KDIM + kc + kq + 4];
        }
        __syncthreads();
        #pragma unroll
        for (int k4 = 0; k4 < K2C / 4; ++k4) {
            float4 a4 = *(const float4*)&As2[rg][k4 * 4];
            #pragma unroll
            for (int c = 0; c < 4; ++c) {
                float4 w4 = *(const float4*)&Ws2[cg * 4 + c][k4 * 4];
                acc[c] = fmaf(a4.x, w4.x, acc[c]);
                acc[c] = fmaf(a4.y, w4.y, acc[c]);
                acc[c] = fmaf(a4.z, w4.z, acc[c]);
                acc[c] = fmaf(a4.w, w4.w, acc[c]);
            }
        }
    }

    float h0 = acc[0] + b2[cg * 4 + 0];
    float h1 = acc[1] + b2[cg * 4 + 1];
    float h2 = acc[2] + b2[cg * 4 + 2];
    float h3 = acc[3] + b2[cg * 4 + 3];
    float s = h0*h0 + h1*h1 + h2*h2 + h3*h3;
    #pragma unroll
    for (int off = 1; off < 8; off <<= 1) s += __shfl_xor(s, off, 8);
    const float den = sqrtf(s + 1e-12f);
    const int r = row0 + rg;
    *(float4*)&Z[(size_t)r * EMB + cg * 4] = make_float4(h0/den, h1/den, h2/den, h3/den);
}

// ---------------------------------------------------------------------------
// K3: per (64-row block, 2048-code split) partial argmin of ||e||^2 - 2 z.e
// Grid (196,4) = 784 blocks x 256 threads, R4-proven 4x8 microtile (acc=32,
// VGPR<=128, 4 waves/SIMD — the only good fp32 operating point; 8x8 @128thr
// crossed the VGPR cliff and regressed, R10).
// NEW: T14 async-stage split — issue tile+1's global loads into regs BEFORE
// computing tile, ds_write them after the post-compute barrier. L2 latency
// (~200-400cy x 16 tiles, previously serial) hides under the FMA loop.
// Unlike R2's spilling variant: single Es buffer, compile-time control flow,
// stage = 4 float4 + 1 float (~17 regs). Est live ~105 VGPR.
// ---------------------------------------------------------------------------
__global__ __launch_bounds__(256) void k3_argmin_part(
    const float* __restrict__ Z, const float* __restrict__ EM,
    const float* __restrict__ N2, float* __restrict__ pminv,
    float* __restrict__ pmini)
{
    __shared__ __align__(16) float Zs[64][36];
    __shared__ __align__(16) float Es[128][36];
    __shared__ float Ns[128];

    const int t     = threadIdx.x;
    const int row0  = blockIdx.x * 64;
    const int cbase = blockIdx.y * 2048;
    const int cg    = t & 15;
    const int rg    = t >> 4;

    const int ec = t >> 3, ekq = (t & 7) * 4;   // this thread stages Es[ec+32i][ekq..+3]

    #pragma unroll
    for (int i = 0; i < 2; ++i) {
        const int fi = t + 256 * i;
        const int r = fi >> 3, kq = fi & 7;
        *(float4*)&Zs[r][kq * 4] = *(const float4*)&Z[(size_t)(row0 + r) * EMB + kq * 4];
    }

    float minv[4] = {INFINITY, INFINITY, INFINITY, INFINITY};
    int   mini[4] = {0, 0, 0, 0};

    // stage tile 0
    float4 pe0, pe1, pe2, pe3;
    float  pn;
    {
        const int tb = cbase;
        pe0 = *(const float4*)&EM[(size_t)(tb + ec) * EMB + ekq];
        pe1 = *(const float4*)&EM[(size_t)(tb + 32 + ec) * EMB + ekq];
        pe2 = *(const float4*)&EM[(size_t)(tb + 64 + ec) * EMB + ekq];
        pe3 = *(const float4*)&EM[(size_t)(tb + 96 + ec) * EMB + ekq];
        if (t < 128) pn = N2[tb + t];
        *(float4*)&Es[ec][ekq]      = pe0;
        *(float4*)&Es[32 + ec][ekq] = pe1;
        *(float4*)&Es[64 + ec][ekq] = pe2;
        *(float4*)&Es[96 + ec][ekq] = pe3;
        if (t < 128) Ns[t] = pn;
    }
    __syncthreads();

    for (int tile = 0; tile < 16; ++tile) {
        const int tb = cbase + tile * 128;
        // T14: issue next tile's loads now; they fly during the FMA loop
        if (tile + 1 < 16) {
            const int nb = tb + 128;
            pe0 = *(const float4*)&EM[(size_t)(nb + ec) * EMB + ekq];
            pe1 = *(const float4*)&EM[(size_t)(nb + 32 + ec) * EMB + ekq];
            pe2 = *(const float4*)&EM[(size_t)(nb + 64 + ec) * EMB + ekq];
            pe3 = *(const float4*)&EM[(size_t)(nb + 96 + ec) * EMB + ekq];
            if (t < 128) pn = N2[nb + t];
        }

        float dot[4][8];
        #pragma unroll
        for (int rr = 0; rr < 4; ++rr)
            #pragma unroll
            for (int cc = 0; cc < 8; ++cc) dot[rr][cc] = 0.f;

        #pragma unroll
        for (int k4 = 0; k4 < 8; ++k4) {
            float4 z4[4];
            #pragma unroll
            for (int rr = 0; rr < 4; ++rr) z4[rr] = *(const float4*)&Zs[rg + 16 * rr][k4 * 4];
            #pragma unroll
            for (int cc = 0; cc < 8; ++cc) {
                float4 e4 = *(const float4*)&Es[cg + 16 * cc][k4 * 4];
                #pragma unroll
                for (int rr = 0; rr < 4; ++rr) {
                    dot[rr][cc] = fmaf(z4[rr].x, e4.x, dot[rr][cc]);
                    dot[rr][cc] = fmaf(z4[rr].y, e4.y, dot[rr][cc]);
                    dot[rr][cc] = fmaf(z4[rr].z, e4.z, dot[rr][cc]);
                    dot[rr][cc] = fmaf(z4[rr].w, e4.w, dot[rr][cc]);
                }
            }
        }
        #pragma unroll
        for (int cc = 0; cc < 8; ++cc) {
            const int cl = cg + 16 * cc;
            const float n2v = Ns[cl];
            const int gi = tb + cl;
            #pragma unroll
            for (int rr = 0; rr < 4; ++rr) {
                const float sc = fmaf(-2.f, dot[rr][cc], n2v);
                if (sc < minv[rr]) { minv[rr] = sc; mini[rr] = gi; }
            }
        }

        __syncthreads();   // everyone done reading Es/Ns
        if (tile + 1 < 16) {
            *(float4*)&Es[ec][ekq]      = pe0;
            *(float4*)&Es[32 + ec][ekq] = pe1;
            *(float4*)&Es[64 + ec][ekq] = pe2;
            *(float4*)&Es[96 + ec][ekq] = pe3;
            if (t < 128) Ns[t] = pn;
            __syncthreads();   // Es ready for next tile
        }
    }

    // reduce across 16 code-group lanes per row; ties -> smaller index
    #pragma unroll
    for (int rr = 0; rr < 4; ++rr) {
        #pragma unroll
        for (int off = 8; off; off >>= 1) {
            const float ov = __shfl_xor(minv[rr], off, 16);
            const int   oi = __shfl_xor(mini[rr], off, 16);
            if (ov < minv[rr] || (ov == minv[rr] && oi < mini[rr])) {
                minv[rr] = ov; mini[rr] = oi;
            }
        }
        if (cg == 0) {
            const int row = row0 + rg + 16 * rr;
            pminv[row * 4 + blockIdx.y] = minv[rr];
            pmini[row * 4 + blockIdx.y] = (float)mini[rr];
        }
    }
}

// ---------------------------------------------------------------------------
// K3b: merge 4 splits per row; write token, z_q (B,32,14,14), loss partials.
// ---------------------------------------------------------------------------
__global__ __launch_bounds__(256) void k3b_merge(
    const float* __restrict__ Z, const float* __restrict__ EM,
    const float* __restrict__ pminv, const float* __restrict__ pmini,
    float* __restrict__ tok, float* __restrict__ zq, float* __restrict__ part)
{
    const int t = threadIdx.x;
    const int row = blockIdx.x * 256 + t;

    float4 mv = *(const float4*)&pminv[row * 4];
    float4 mi = *(const float4*)&pmini[row * 4];
    float best = mv.x; int bi = (int)mi.x;
    if (mv.y < best) { best = mv.y; bi = (int)mi.y; }
    if (mv.z < best) { best = mv.z; bi = (int)mi.z; }
    if (mv.w < best) { best = mv.w; bi = (int)mi.w; }
    tok[row] = (float)bi;

    const int b = row / 196, n = row % 196;
    float lp = 0.f;
    #pragma unroll
    for (int q = 0; q < 8; ++q) {
        float4 e = *(const float4*)&EM[(size_t)bi * EMB + q * 4];
        float4 z = *(const float4*)&Z[(size_t)row * EMB + q * 4];
        float d0 = e.x - z.x, d1 = e.y - z.y, d2 = e.z - z.z, d3 = e.w - z.w;
        lp = fmaf(d0, d0, lp); lp = fmaf(d1, d1, lp);
        lp = fmaf(d2, d2, lp); lp = fmaf(d3, d3, lp);
        const size_t zb = (size_t)b * 6272 + n;
        zq[zb + (q * 4 + 0) * 196] = e.x;
        zq[zb + (q * 4 + 1) * 196] = e.y;
        zq[zb + (q * 4 + 2) * 196] = e.z;
        zq[zb + (q * 4 + 3) * 196] = e.w;
    }
    #pragma unroll
    for (int off = 32; off; off >>= 1) lp += __shfl_xor(lp, off, 64);
    __shared__ float r4[4];
    if ((t & 63) == 0) r4[t >> 6] = lp;
    __syncthreads();
    if (t == 0) part[blockIdx.x] = r4[0] + r4[1] + r4[2] + r4[3];
}

// ---------------------------------------------------------------------------
// K4: deterministic loss reduce over 49 partials
// ---------------------------------------------------------------------------
__global__ __launch_bounds__(64) void k4_loss(
    const float* __restrict__ part, float* __restrict__ loss)
{
    const int t = threadIdx.x;
    float v = (t < 49) ? part[t] : 0.f;
    #pragma unroll
    for (int off = 32; off; off >>= 1) v += __shfl_xor(v, off, 64);
    if (t == 0) loss[0] = v * (1.0f / 401408.f);
}

// ---------------------------------------------------------------------------
extern "C" void kernel_launch(void* const* d_in, const int* in_sizes, int n_in,
                              void* d_out, int out_size, void* d_ws, size_t ws_size,
                              hipStream_t stream)
{
    (void)in_sizes; (void)n_in; (void)out_size; (void)ws_size;
    const float* features = (const float*)d_in[0];
    const float* w1 = (const float*)d_in[1];
    const float* b1 = (const float*)d_in[2];
    const float* w2 = (const float*)d_in[3];
    const float* b2 = (const float*)d_in[4];
    const float* cb = (const float*)d_in[5];

    float* out  = (float*)d_out;
    float* tok  = out;                       // 12544
    float* zq   = out + MROWS;               // 401408
    float* loss = out + MROWS + ZQ_ELEMS;    // 1

    float* ws   = (float*)d_ws;
    float* H    = ws;                         // 12544*768
    float* Zb   = H + (size_t)MROWS * KDIM;   // 12544*32
    float* EM   = Zb + (size_t)MROWS * EMB;   // 8192*32
    float* N2   = EM + (size_t)NCODE * EMB;   // 8192
    float* PART = N2 + NCODE;                 // 64
    // H is dead after K2 -> reuse its space for the per-split argmin pairs
    float* PMINV = H;                         // 12544*4
    float* PMINI = H + (size_t)MROWS * 4;     // 12544*4

    k0_norm_codebook<<<NCODE / 8, 256, 0, stream>>>(cb, EM, N2);
    k1_gemm_tanh<<<dim3(MROWS / BM1, KDIM / BN1), 256, 0, stream>>>(features, w1, b1, H);
    k2_gemm_norm<<<MROWS / 32, 256, 0, stream>>>(H, w2, b2, Zb);
    k3_argmin_part<<<dim3(MROWS / 64, 4), 256, 0, stream>>>(Zb, EM, N2, PMINV, PMINI);
    k3b_merge<<<MROWS / 256, 256, 0, stream>>>(Zb, EM, PMINV, PMINI, tok, zq, PART);
    k4_loss<<<1, 64, 0, stream>>>(PART, loss);
}

// Round 12
// 448.353 us; speedup vs baseline: 1.1278x; 1.1278x over previous
//
#include <hip/hip_runtime.h>
#include <math.h>

#define MROWS 12544        // B*N = 64*196
#define KDIM  768
#define EMB   32
#define NCODE 8192
#define ZQ_ELEMS 401408    // 64*32*14*14

// ---------------------------------------------------------------------------
// K0: normalize codebook rows; also store ||e||^2 (post-normalization, as ref)
// ---------------------------------------------------------------------------
__global__ __launch_bounds__(256) void k0_norm_codebook(
    const float* __restrict__ cb, float* __restrict__ em, float* __restrict__ n2)
{
    const int t = threadIdx.x;
    const int c = t & 31;
    const int r = blockIdx.x * 8 + (t >> 5);
    float v = cb[r * 32 + c];
    float s = v * v;
    #pragma unroll
    for (int off = 16; off; off >>= 1) s += __shfl_xor(s, off, 32);
    float e = v / sqrtf(s + 1e-12f);
    em[r * 32 + c] = e;
    float s2 = e * e;
    #pragma unroll
    for (int off = 16; off; off >>= 1) s2 += __shfl_xor(s2, off, 32);
    if (c == 0) n2[r] = s2;
}

// ---------------------------------------------------------------------------
// K1: H = tanh(X @ W1^T + b1).  R4 operating point (PROVEN 248us):
// 64x128 tile, BK=16, 256 threads, 4x8 microtile, one-arg launch_bounds ->
// VGPR 128, 4 waves/SIMD. LDS-issue-bound (~85% LDS pipe); any acc>32
// microtile crosses the 128-VGPR cliff to 2 waves/SIMD and loses (R8/R9);
// two-arg launch_bounds or no launch_bounds forces VGPR=64 + GB-scale
// spill (R3/R6/R7). Do not touch.
// ---------------------------------------------------------------------------
#define BM1 64
#define BN1 128
#define BK1 16

__global__ __launch_bounds__(256) void k1_gemm_tanh(
    const float* __restrict__ A, const float* __restrict__ W,
    const float* __restrict__ bias, float* __restrict__ H)
{
    __shared__ __align__(16) float As[2][BK1][68];
    __shared__ __align__(16) float Bs[2][BK1][132];

    const int t    = threadIdx.x;
    const int row0 = blockIdx.x * BM1;
    const int col0 = blockIdx.y * BN1;
    const int tc   = t & 15;          // col group: cols tc*4..+3 and 64+tc*4..+3
    const int tr   = t >> 4;          // row group: rows tr*4..+3

    const int am = t >> 2, ak = (t & 3) * 4;   // A stage: row am, k ak..ak+3
    const int bn = t >> 1, bk = (t & 1) * 8;   // B stage: row bn, k bk..bk+7

    const float* Ap = A + (size_t)(row0 + am) * KDIM + ak;
    const float* Bp = W + (size_t)(col0 + bn) * KDIM + bk;

    float acc[4][8];
    #pragma unroll
    for (int i = 0; i < 4; ++i)
        #pragma unroll
        for (int j = 0; j < 8; ++j) acc[i][j] = 0.f;

    // preload tile 0 (transposed into LDS)
    {
        float4 a  = *(const float4*)(Ap);
        float4 b0 = *(const float4*)(Bp);
        float4 b1 = *(const float4*)(Bp + 4);
        As[0][ak+0][am] = a.x;  As[0][ak+1][am] = a.y;  As[0][ak+2][am] = a.z;  As[0][ak+3][am] = a.w;
        Bs[0][bk+0][bn] = b0.x; Bs[0][bk+1][bn] = b0.y; Bs[0][bk+2][bn] = b0.z; Bs[0][bk+3][bn] = b0.w;
        Bs[0][bk+4][bn] = b1.x; Bs[0][bk+5][bn] = b1.y; Bs[0][bk+6][bn] = b1.z; Bs[0][bk+7][bn] = b1.w;
    }
    __syncthreads();

    const int nkt = KDIM / BK1;   // 48
    int buf = 0;
    for (int kt = 0; kt < nkt; ++kt) {
        float4 na, nb0, nb1;
        const bool pf = (kt + 1 < nkt);
        if (pf) {
            const int ko = (kt + 1) * BK1;
            na  = *(const float4*)(Ap + ko);
            nb0 = *(const float4*)(Bp + ko);
            nb1 = *(const float4*)(Bp + ko + 4);
        }
        #pragma unroll
        for (int k = 0; k < BK1; ++k) {
            float4 av  = *(const float4*)&As[buf][k][tr * 4];
            float4 bv0 = *(const float4*)&Bs[buf][k][tc * 4];
            float4 bv1 = *(const float4*)&Bs[buf][k][tc * 4 + 64];
            float a_[4] = {av.x, av.y, av.z, av.w};
            float b_[8] = {bv0.x, bv0.y, bv0.z, bv0.w, bv1.x, bv1.y, bv1.z, bv1.w};
            #pragma unroll
            for (int i = 0; i < 4; ++i)
                #pragma unroll
                for (int j = 0; j < 8; ++j)
                    acc[i][j] = fmaf(a_[i], b_[j], acc[i][j]);
        }
        if (pf) {
            const int nb = buf ^ 1;
            As[nb][ak+0][am] = na.x;  As[nb][ak+1][am] = na.y;  As[nb][ak+2][am] = na.z;  As[nb][ak+3][am] = na.w;
            Bs[nb][bk+0][bn] = nb0.x; Bs[nb][bk+1][bn] = nb0.y; Bs[nb][bk+2][bn] = nb0.z; Bs[nb][bk+3][bn] = nb0.w;
            Bs[nb][bk+4][bn] = nb1.x; Bs[nb][bk+5][bn] = nb1.y; Bs[nb][bk+6][bn] = nb1.z; Bs[nb][bk+7][bn] = nb1.w;
        }
        __syncthreads();
        buf ^= 1;
    }

    float4 bc0 = *(const float4*)&bias[col0 + tc * 4];
    float4 bc1 = *(const float4*)&bias[col0 + 64 + tc * 4];
    #pragma unroll
    for (int i = 0; i < 4; ++i) {
        const int row = row0 + tr * 4 + i;
        float o0 = tanhf(acc[i][0] + bc0.x);
        float o1 = tanhf(acc[i][1] + bc0.y);
        float o2 = tanhf(acc[i][2] + bc0.z);
        float o3 = tanhf(acc[i][3] + bc0.w);
        float o4 = tanhf(acc[i][4] + bc1.x);
        float o5 = tanhf(acc[i][5] + bc1.y);
        float o6 = tanhf(acc[i][6] + bc1.z);
        float o7 = tanhf(acc[i][7] + bc1.w);
        *(float4*)&H[(size_t)row * KDIM + col0 + tc * 4]      = make_float4(o0, o1, o2, o3);
        *(float4*)&H[(size_t)row * KDIM + col0 + 64 + tc * 4] = make_float4(o4, o5, o6, o7);
    }
}

// ---------------------------------------------------------------------------
// K2: Z = l2norm(H @ W2^T + b2).  32 rows/block -> 392 blocks.
// ---------------------------------------------------------------------------
#define K2C 64
__global__ __launch_bounds__(256) void k2_gemm_norm(
    const float* __restrict__ H, const float* __restrict__ W2,
    const float* __restrict__ b2, float* __restrict__ Z)
{
    __shared__ __align__(16) float As2[32][68];
    __shared__ __align__(16) float Ws2[32][68];

    const int t    = threadIdx.x;
    const int row0 = blockIdx.x * 32;
    const int cg   = t & 7;
    const int rg   = t >> 3;

    float acc[4] = {0.f, 0.f, 0.f, 0.f};

    for (int kc = 0; kc < KDIM; kc += K2C) {
        __syncthreads();
        {
            const int r = t >> 3, kq = (t & 7) * 8;
            *(float4*)&As2[r][kq]     = *(const float4*)&H[(size_t)(row0 + r) * KDIM + kc + kq];
            *(float4*)&As2[r][kq + 4] = *(const float4*)&H[(size_t)(row0 + r) * KDIM + kc + kq + 4];
            *(float4*)&Ws2[r][kq]     = *(const float4*)&W2[(size_t)r * KDIM + kc + kq];
            *(float4*)&Ws2[r][kq + 4] = *(const float4*)&W2[(size_t)r * KDIM + kc + kq + 4];
        }
        __syncthreads();
        #pragma unroll
        for (int k4 = 0; k4 < K2C / 4; ++k4) {
            float4 a4 = *(const float4*)&As2[rg][k4 * 4];
            #pragma unroll
            for (int c = 0; c < 4; ++c) {
                float4 w4 = *(const float4*)&Ws2[cg * 4 + c][k4 * 4];
                acc[c] = fmaf(a4.x, w4.x, acc[c]);
                acc[c] = fmaf(a4.y, w4.y, acc[c]);
                acc[c] = fmaf(a4.z, w4.z, acc[c]);
                acc[c] = fmaf(a4.w, w4.w, acc[c]);
            }
        }
    }

    float h0 = acc[0] + b2[cg * 4 + 0];
    float h1 = acc[1] + b2[cg * 4 + 1];
    float h2 = acc[2] + b2[cg * 4 + 2];
    float h3 = acc[3] + b2[cg * 4 + 3];
    float s = h0*h0 + h1*h1 + h2*h2 + h3*h3;
    #pragma unroll
    for (int off = 1; off < 8; off <<= 1) s += __shfl_xor(s, off, 8);
    const float den = sqrtf(s + 1e-12f);
    const int r = row0 + rg;
    *(float4*)&Z[(size_t)r * EMB + cg * 4] = make_float4(h0/den, h1/den, h2/den, h3/den);
}

// ---------------------------------------------------------------------------
// K3: per (64-row block, 2048-code split) partial argmin of ||e||^2 - 2 z.e
// R4-EXACT (proven): grid (196,4) x 256 threads, 4x8 microtile, single-
// buffered staging. acc=32 keeps VGPR ~100 -> 4 waves/SIMD. Both attempted
// "improvements" (8x8 @128thr R10; T14 reg-stage R11) crossed the 128-VGPR
// cliff and regressed. LDS-issue floor ~94us + barrier overhead.
// ---------------------------------------------------------------------------
__global__ __launch_bounds__(256) void k3_argmin_part(
    const float* __restrict__ Z, const float* __restrict__ EM,
    const float* __restrict__ N2, float* __restrict__ pminv,
    float* __restrict__ pmini)
{
    __shared__ __align__(16) float Zs[64][36];
    __shared__ __align__(16) float Es[128][36];
    __shared__ float Ns[128];

    const int t     = threadIdx.x;
    const int row0  = blockIdx.x * 64;
    const int cbase = blockIdx.y * 2048;
    const int cg    = t & 15;
    const int rg    = t >> 4;

    #pragma unroll
    for (int i = 0; i < 2; ++i) {
        const int fi = t + 256 * i;
        const int r = fi >> 3, kq = fi & 7;
        *(float4*)&Zs[r][kq * 4] = *(const float4*)&Z[(size_t)(row0 + r) * EMB + kq * 4];
    }

    float minv[4] = {INFINITY, INFINITY, INFINITY, INFINITY};
    int   mini[4] = {0, 0, 0, 0};

    for (int tile = 0; tile < 16; ++tile) {
        __syncthreads();
        const int tb = cbase + tile * 128;
        #pragma unroll
        for (int i = 0; i < 4; ++i) {
            const int fi = t + 256 * i;
            const int c = fi >> 3, kq = fi & 7;
            *(float4*)&Es[c][kq * 4] = *(const float4*)&EM[(size_t)(tb + c) * EMB + kq * 4];
        }
        if (t < 128) Ns[t] = N2[tb + t];
        __syncthreads();

        float dot[4][8];
        #pragma unroll
        for (int rr = 0; rr < 4; ++rr)
            #pragma unroll
            for (int cc = 0; cc < 8; ++cc) dot[rr][cc] = 0.f;

        #pragma unroll
        for (int k4 = 0; k4 < 8; ++k4) {
            float4 z4[4];
            #pragma unroll
            for (int rr = 0; rr < 4; ++rr) z4[rr] = *(const float4*)&Zs[rg + 16 * rr][k4 * 4];
            #pragma unroll
            for (int cc = 0; cc < 8; ++cc) {
                float4 e4 = *(const float4*)&Es[cg + 16 * cc][k4 * 4];
                #pragma unroll
                for (int rr = 0; rr < 4; ++rr) {
                    dot[rr][cc] = fmaf(z4[rr].x, e4.x, dot[rr][cc]);
                    dot[rr][cc] = fmaf(z4[rr].y, e4.y, dot[rr][cc]);
                    dot[rr][cc] = fmaf(z4[rr].z, e4.z, dot[rr][cc]);
                    dot[rr][cc] = fmaf(z4[rr].w, e4.w, dot[rr][cc]);
                }
            }
        }
        #pragma unroll
        for (int cc = 0; cc < 8; ++cc) {
            const int cl = cg + 16 * cc;
            const float n2v = Ns[cl];
            const int gi = tb + cl;
            #pragma unroll
            for (int rr = 0; rr < 4; ++rr) {
                const float sc = fmaf(-2.f, dot[rr][cc], n2v);
                if (sc < minv[rr]) { minv[rr] = sc; mini[rr] = gi; }
            }
        }
    }

    // reduce across 16 code-group lanes per row; ties -> smaller index
    #pragma unroll
    for (int rr = 0; rr < 4; ++rr) {
        #pragma unroll
        for (int off = 8; off; off >>= 1) {
            const float ov = __shfl_xor(minv[rr], off, 16);
            const int   oi = __shfl_xor(mini[rr], off, 16);
            if (ov < minv[rr] || (ov == minv[rr] && oi < mini[rr])) {
                minv[rr] = ov; mini[rr] = oi;
            }
        }
        if (cg == 0) {
            const int row = row0 + rg + 16 * rr;
            pminv[row * 4 + blockIdx.y] = minv[rr];
            pmini[row * 4 + blockIdx.y] = (float)mini[rr];
        }
    }
}

// ---------------------------------------------------------------------------
// K3b: merge 4 splits per row; write token, z_q (B,32,14,14), loss partials.
// ---------------------------------------------------------------------------
__global__ __launch_bounds__(256) void k3b_merge(
    const float* __restrict__ Z, const float* __restrict__ EM,
    const float* __restrict__ pminv, const float* __restrict__ pmini,
    float* __restrict__ tok, float* __restrict__ zq, float* __restrict__ part)
{
    const int t = threadIdx.x;
    const int row = blockIdx.x * 256 + t;

    float4 mv = *(const float4*)&pminv[row * 4];
    float4 mi = *(const float4*)&pmini[row * 4];
    float best = mv.x; int bi = (int)mi.x;
    if (mv.y < best) { best = mv.y; bi = (int)mi.y; }
    if (mv.z < best) { best = mv.z; bi = (int)mi.z; }
    if (mv.w < best) { best = mv.w; bi = (int)mi.w; }
    tok[row] = (float)bi;

    const int b = row / 196, n = row % 196;
    float lp = 0.f;
    #pragma unroll
    for (int q = 0; q < 8; ++q) {
        float4 e = *(const float4*)&EM[(size_t)bi * EMB + q * 4];
        float4 z = *(const float4*)&Z[(size_t)row * EMB + q * 4];
        float d0 = e.x - z.x, d1 = e.y - z.y, d2 = e.z - z.z, d3 = e.w - z.w;
        lp = fmaf(d0, d0, lp); lp = fmaf(d1, d1, lp);
        lp = fmaf(d2, d2, lp); lp = fmaf(d3, d3, lp);
        const size_t zb = (size_t)b * 6272 + n;
        zq[zb + (q * 4 + 0) * 196] = e.x;
        zq[zb + (q * 4 + 1) * 196] = e.y;
        zq[zb + (q * 4 + 2) * 196] = e.z;
        zq[zb + (q * 4 + 3) * 196] = e.w;
    }
    #pragma unroll
    for (int off = 32; off; off >>= 1) lp += __shfl_xor(lp, off, 64);
    __shared__ float r4[4];
    if ((t & 63) == 0) r4[t >> 6] = lp;
    __syncthreads();
    if (t == 0) part[blockIdx.x] = r4[0] + r4[1] + r4[2] + r4[3];
}

// ---------------------------------------------------------------------------
// K4: deterministic loss reduce over 49 partials
// ---------------------------------------------------------------------------
__global__ __launch_bounds__(64) void k4_loss(
    const float* __restrict__ part, float* __restrict__ loss)
{
    const int t = threadIdx.x;
    float v = (t < 49) ? part[t] : 0.f;
    #pragma unroll
    for (int off = 32; off; off >>= 1) v += __shfl_xor(v, off, 64);
    if (t == 0) loss[0] = v * (1.0f / 401408.f);
}

// ---------------------------------------------------------------------------
extern "C" void kernel_launch(void* const* d_in, const int* in_sizes, int n_in,
                              void* d_out, int out_size, void* d_ws, size_t ws_size,
                              hipStream_t stream)
{
    (void)in_sizes; (void)n_in; (void)out_size; (void)ws_size;
    const float* features = (const float*)d_in[0];
    const float* w1 = (const float*)d_in[1];
    const float* b1 = (const float*)d_in[2];
    const float* w2 = (const float*)d_in[3];
    const float* b2 = (const float*)d_in[4];
    const float* cb = (const float*)d_in[5];

    float* out  = (float*)d_out;
    float* tok  = out;                       // 12544
    float* zq   = out + MROWS;               // 401408
    float* loss = out + MROWS + ZQ_ELEMS;    // 1

    float* ws   = (float*)d_ws;
    float* H    = ws;                         // 12544*768
    float* Zb   = H + (size_t)MROWS * KDIM;   // 12544*32
    float* EM   = Zb + (size_t)MROWS * EMB;   // 8192*32
    float* N2   = EM + (size_t)NCODE * EMB;   // 8192
    float* PART = N2 + NCODE;                 // 64
    // H is dead after K2 -> reuse its space for the per-split argmin pairs
    float* PMINV = H;                         // 12544*4
    float* PMINI = H + (size_t)MROWS * 4;     // 12544*4

    k0_norm_codebook<<<NCODE / 8, 256, 0, stream>>>(cb, EM, N2);
    k1_gemm_tanh<<<dim3(MROWS / BM1, KDIM / BN1), 256, 0, stream>>>(features, w1, b1, H);
    k2_gemm_norm<<<MROWS / 32, 256, 0, stream>>>(H, w2, b2, Zb);
    k3_argmin_part<<<dim3(MROWS / 64, 4), 256, 0, stream>>>(Zb, EM, N2, PMINV, PMINI);
    k3b_merge<<<MROWS / 256, 256, 0, stream>>>(Zb, EM, PMINV, PMINI, tok, zq, PART);
    k4_loss<<<1, 64, 0, stream>>>(PART, loss);
}